// Round 4
// baseline (172.576 us; speedup 1.0000x reference)
//
#include <hip/hip_runtime.h>
#include <cstdint>
#include <cstddef>

typedef short bf16x8 __attribute__((ext_vector_type(8)));
typedef float f32x4 __attribute__((ext_vector_type(4)));

#define EPS 1e-3f

__device__ __forceinline__ short f32_to_bf16s(float f) {
    union { float f; uint32_t u; } v; v.f = f;
    uint32_t u = v.u;
    return (short)((u + 0x7FFFu + ((u >> 16) & 1u)) >> 16);
}

// K0: wt[kp][ci] = bf16(W[ci][kp]) (192x64); at[w][k] = bf16(A[p][v][w]) (32x96, k=p*25+v, zero-padded)
__global__ __launch_bounds__(256) void prep_kernel(const float* __restrict__ A,
                                                   const float* __restrict__ W,
                                                   unsigned short* __restrict__ wt,
                                                   unsigned short* __restrict__ at) {
    int idx = blockIdx.x * 256 + threadIdx.x;
    if (idx < 12288) {
        int kp = idx >> 6, ci = idx & 63;
        wt[idx] = (unsigned short)f32_to_bf16s(W[ci * 192 + kp]);
    } else {
        int j = idx - 12288;
        if (j < 3072) {
            int w = j / 96, k = j - w * 96;
            float val = 0.f;
            if (w < 25 && k < 75) {
                int p = k / 25, v = k - p * 25;
                val = A[(p * 25 + v) * 25 + w];
            }
            at[j] = (unsigned short)f32_to_bf16s(val);
        }
    }
}

// Mega: in-LDS temporal window + conv(1x1) GEMM + graph GEMM + BN/ReLU/residual/ReLU.
// Block = (l-chunk of 10, n), 512 threads (8 waves).
// LDS union: phase 1/2 -> xwL[qs=ci>>3][col=l*25+v][j=ci&7], row stride 2056 shorts;
//            phase 3+  -> Ys[l*16+cl][104] (k=p*25+v, pad zeroed).
__global__ __launch_bounds__(512, 4) void mega_kernel(
    const float* __restrict__ x,
    const unsigned short* __restrict__ wt,
    const unsigned short* __restrict__ at,
    const float* __restrict__ gamma, const float* __restrict__ beta,
    const float* __restrict__ mean, const float* __restrict__ var,
    float* __restrict__ out) {
    int ch = blockIdx.x, n = blockIdx.y;
    int l0 = ch * 10;
    int tid = threadIdx.x;
    int wv = tid >> 6, lane = tid & 63, q = lane >> 4, lcol = lane & 15;

    __shared__ short smem[16640];          // 33,280 B (max of xwL 16392 / Ys 16640 shorts)
    __shared__ float scs[64], shs[64];

    if (tid < 64) {
        float sc = gamma[tid] * rsqrtf(var[tid] + EPS);
        scs[tid] = sc;
        shs[tid] = beta[tid] - mean[tid] * sc;
    }

    // Phase 1: per-column (ci,v) running 9-window, l = l0..l0+9 -> xwL (bf16).
    // Batched: 3 columns/thread, ALL 54 loads in flight before any arithmetic.
    {
        float va[3][18];
        #pragma unroll
        for (int rep = 0; rep < 3; ++rep) {
            int cidx = tid + rep * 512;            // < 1536
            int ci = cidx / 25, v = cidx - ci * 25;
            const float* xp = x + (size_t)(n * 64 + ci) * 7500 + v;
            #pragma unroll
            for (int i = 0; i < 18; ++i) {
                int l = l0 - 8 + i;
                va[rep][i] = (l >= 0) ? xp[l * 25] : 0.f;   // l0+9 <= 299 always
            }
        }
        #pragma unroll
        for (int rep = 0; rep < 3; ++rep) {
            int cidx = tid + rep * 512;
            int ci = cidx / 25, v = cidx - ci * 25;
            float run = 0.f;
            #pragma unroll
            for (int i = 0; i < 8; ++i) run += va[rep][i];
            int base = (ci >> 3) * 2056 + (ci & 7);
            #pragma unroll
            for (int j = 0; j < 10; ++j) {
                run += va[rep][j + 8];
                smem[base + (j * 25 + v) * 8] = f32_to_bf16s(run);
                run -= va[rep][j];
            }
        }
        if (tid < 64) {                             // tail: columns 1536..1599 (wave 0)
            int cidx = 1536 + tid;
            int ci = cidx / 25, v = cidx - ci * 25;
            const float* xp = x + (size_t)(n * 64 + ci) * 7500 + v;
            float vt[18];
            #pragma unroll
            for (int i = 0; i < 18; ++i) {
                int l = l0 - 8 + i;
                vt[i] = (l >= 0) ? xp[l * 25] : 0.f;
            }
            float run = 0.f;
            #pragma unroll
            for (int i = 0; i < 8; ++i) run += vt[i];
            int base = (ci >> 3) * 2056 + (ci & 7);
            #pragma unroll
            for (int j = 0; j < 10; ++j) {
                run += vt[j + 8];
                smem[base + (j * 25 + v) * 8] = f32_to_bf16s(run);
                run -= vt[j];
            }
        }
    }
    __syncthreads();

    // B1 fragments (GEMM1): k = 32s+8q+j, col = wv*32 + nt*16 + lcol  -> aligned ds_read_b128
    bf16x8 b1[2][2];
    #pragma unroll
    for (int nt = 0; nt < 2; ++nt)
        #pragma unroll
        for (int s = 0; s < 2; ++s) {
            int col = wv * 32 + nt * 16 + lcol;
            b1[nt][s] = *(const bf16x8*)&smem[(4 * s + q) * 2056 + col * 8];
        }
    // B2 fragments (GEMM2): at[w][k], block-invariant, from L2
    bf16x8 b2[2][3];
    #pragma unroll
    for (int nt = 0; nt < 2; ++nt)
        #pragma unroll
        for (int s = 0; s < 3; ++s)
            b2[nt][s] = *(const bf16x8*)(at + (size_t)(nt * 16 + lcol) * 96 + 32 * s + 8 * q);
    __syncthreads();   // xwL fully consumed; smem becomes Ys

    // zero Ys pad region k in [72,104) (MFMA reads k<96; staging never writes pad)
    for (int i = tid; i < 5120; i += 512) {
        int r = i >> 5, jj = 72 + (i & 31);
        smem[r * 104 + jj] = 0;
    }

    for (int g = 0; g < 4; ++g) {
        // GEMM1: M=48 (kp rows of c-group g), N=256, K=64
        f32x4 acc[3][2];
        #pragma unroll
        for (int mt = 0; mt < 3; ++mt)
            #pragma unroll
            for (int nt = 0; nt < 2; ++nt) acc[mt][nt] = (f32x4){0.f, 0.f, 0.f, 0.f};
        #pragma unroll
        for (int s = 0; s < 2; ++s)
            #pragma unroll
            for (int mt = 0; mt < 3; ++mt) {
                bf16x8 a1 = *(const bf16x8*)(wt + (size_t)(g * 48 + mt * 16 + lcol) * 64 + 32 * s + 8 * q);
                #pragma unroll
                for (int nt = 0; nt < 2; ++nt)
                    acc[mt][nt] = __builtin_amdgcn_mfma_f32_16x16x32_bf16(a1, b1[nt][s], acc[mt][nt], 0, 0, 0);
            }

        // Residual x prefetch for this group's GEMM2 jobs (latency absorbed by barrier+staging)
        float xres[3][4];
        size_t gbase[3];
        #pragma unroll
        for (int t = 0; t < 3; ++t) {
            int j = wv + 8 * t;
            int l = j >> 1, nt = j & 1;
            int w = nt * 16 + lcol;
            bool valid = (j < 20) && (w < 25);
            int c0 = g * 16 + 4 * q;
            size_t gi0 = ((size_t)(n * 64 + c0) * 300 + (l0 + l)) * 25 + w;
            gbase[t] = gi0;
            #pragma unroll
            for (int r = 0; r < 4; ++r)
                xres[t][r] = valid ? x[gi0 + (size_t)r * 7500] : 0.f;
        }

        __syncthreads();   // previous group's GEMM2 reads done; Ys free
        // Stage D -> Ys[l][cl][p*25+v]
        #pragma unroll
        for (int mt = 0; mt < 3; ++mt)
            #pragma unroll
            for (int nt = 0; nt < 2; ++nt) {
                int col = wv * 32 + nt * 16 + lcol;
                if (col < 250) {
                    int ll = col / 25, v = col - ll * 25;
                    #pragma unroll
                    for (int r = 0; r < 4; ++r) {
                        int kp = mt * 16 + 4 * q + r;
                        int cl = kp / 3, p = kp - cl * 3;
                        smem[(ll * 16 + cl) * 104 + p * 25 + v] = f32_to_bf16s(acc[mt][nt][r]);
                    }
                }
            }
        __syncthreads();

        // GEMM2: 20 jobs (l, nt), job j = wv + 8t -> max 3 jobs/wave, balanced
        #pragma unroll
        for (int t = 0; t < 3; ++t) {
            int j = wv + 8 * t;
            if (j < 20) {
                int l = j >> 1, nt = j & 1;
                int w = nt * 16 + lcol;
                f32x4 cacc = {0.f, 0.f, 0.f, 0.f};
                #pragma unroll
                for (int s = 0; s < 3; ++s) {
                    bf16x8 a2 = *(const bf16x8*)&smem[(l * 16 + lcol) * 104 + 32 * s + 8 * q];
                    cacc = __builtin_amdgcn_mfma_f32_16x16x32_bf16(a2, b2[nt][s], cacc, 0, 0, 0);
                }
                if (w < 25) {
                    #pragma unroll
                    for (int r = 0; r < 4; ++r) {
                        int c = g * 16 + 4 * q + r;
                        float o = fmaxf(cacc[r] * scs[c] + shs[c], 0.f);
                        float res = fmaxf(o + xres[t][r], 0.f);
                        __builtin_nontemporal_store(res, &out[gbase[t] + (size_t)r * 7500]);
                    }
                }
            }
        }
    }
}

extern "C" void kernel_launch(void* const* d_in, const int* in_sizes, int n_in,
                              void* d_out, int out_size, void* d_ws, size_t ws_size,
                              hipStream_t stream) {
    const float* x     = (const float*)d_in[0];
    const float* A     = (const float*)d_in[1];
    const float* W     = (const float*)d_in[2];
    const float* gamma = (const float*)d_in[3];
    const float* beta  = (const float*)d_in[4];
    const float* mean  = (const float*)d_in[5];
    const float* var   = (const float*)d_in[6];
    float* out = (float*)d_out;

    char* ws = (char*)d_ws;
    unsigned short* wt = (unsigned short*)ws;               // 24,576 B
    unsigned short* at = (unsigned short*)(ws + 24576);     // 6,144 B

    prep_kernel<<<60, 256, 0, stream>>>(A, W, wt, at);
    mega_kernel<<<dim3(30, 32), 512, 0, stream>>>(x, wt, at, gamma, beta, mean, var, out);
}